// Round 10
// baseline (363.669 us; speedup 1.0000x reference)
//
#include <hip/hip_runtime.h>
#include <hip/hip_bf16.h>

typedef __bf16 bf16_t;
typedef __bf16 bf16x8 __attribute__((ext_vector_type(8)));
typedef __bf16 bf16x4 __attribute__((ext_vector_type(4)));
typedef float f32x4 __attribute__((ext_vector_type(4)));
typedef float f32x16 __attribute__((ext_vector_type(16)));
typedef unsigned int u32x4 __attribute__((ext_vector_type(4)));

#define AS1(p) ((const __attribute__((address_space(1))) void*)(p))
#define AS3(p) ((__attribute__((address_space(3))) void*)(p))

// scale = HEAD_DIM^-0.5 * log2(e), folded into Q at QKV-GEMM epilogue
#define QSCALE 0.1803368801111204f

// ---------------- fused prep: cast X + transpose/cast both W (one launch) ----------------
__global__ __launch_bounds__(256) void prep_kernel(
    const float* __restrict__ X, bf16_t* __restrict__ Xb,
    const float* __restrict__ Wqkv, bf16_t* __restrict__ Wqkvt,
    const float* __restrict__ Wout, bf16_t* __restrict__ Woutt) {
  __shared__ float tile[32][33];
  int bid = blockIdx.x;
  if (bid < 8192) {
    int i = (bid * 256 + threadIdx.x) * 4;
    float4 v = *(const float4*)(X + i);
    bf16x4 o;
    o[0] = (bf16_t)v.x; o[1] = (bf16_t)v.y; o[2] = (bf16_t)v.z; o[3] = (bf16_t)v.w;
    *(bf16x4*)(Xb + i) = o;
    return;
  }
  bid -= 8192;
  const float* W; bf16_t* Wt; int N, bx, by;
  if (bid < 3072) { W = Wqkv; Wt = Wqkvt; N = 3072; bx = bid % 96; by = bid / 96; }
  else { bid -= 3072; W = Wout; Wt = Woutt; N = 1024; bx = bid & 31; by = bid >> 5; }
  const int K = 1024;
  int tx = threadIdx.x & 31, ty = threadIdx.x >> 5;
  int n0 = bx * 32, k0 = by * 32;
  for (int r = ty; r < 32; r += 8)
    tile[r][tx] = W[(size_t)(k0 + r) * N + n0 + tx];
  __syncthreads();
  for (int r = ty; r < 32; r += 8)
    Wt[(size_t)(n0 + r) * K + k0 + tx] = (bf16_t)tile[tx][r];
}

// ---------------- QKV GEMM: C[8192,3072] = Xb[8192,1024] @ Wt[3072,1024]^T ----------------
__global__ __launch_bounds__(256) void gemm_qkv_kernel(
    const bf16_t* __restrict__ A, const bf16_t* __restrict__ Bt,
    bf16_t* __restrict__ Qb, bf16_t* __restrict__ Kb, bf16_t* __restrict__ Vt) {
  __shared__ __align__(16) bf16_t As[128 * 32];
  __shared__ __align__(16) bf16_t Bs[128 * 32];
  const int tid = threadIdx.x;
  const int lane = tid & 63, wave = tid >> 6;
  const int quad = lane >> 4, l15 = lane & 15;
  const int wr = wave >> 1, wc = wave & 1;
  const int m0 = blockIdx.x * 128, n0 = blockIdx.y * 128;
  f32x4 acc[4][4];
  const f32x4 vzero = {0.f, 0.f, 0.f, 0.f};
#pragma unroll
  for (int i = 0; i < 4; i++)
#pragma unroll
    for (int j = 0; j < 4; j++) acc[i][j] = vzero;

  for (int kb = 0; kb < 1024; kb += 32) {
    __syncthreads();
#pragma unroll
    for (int i = 0; i < 2; i++) {
      int c = i * 256 + tid;
      int row = c >> 2, kc = c & 3;
      __builtin_amdgcn_global_load_lds(AS1(A + (size_t)(m0 + row) * 1024 + kb + kc * 8),
                                       AS3(As + c * 8), 16, 0, 0);
    }
#pragma unroll
    for (int i = 0; i < 2; i++) {
      int c = i * 256 + tid;
      int row = c >> 2, kc = c & 3;
      __builtin_amdgcn_global_load_lds(AS1(Bt + (size_t)(n0 + row) * 1024 + kb + kc * 8),
                                       AS3(Bs + c * 8), 16, 0, 0);
    }
    __builtin_amdgcn_s_waitcnt(0);
    __syncthreads();
    bf16x8 af[4], bfr[4];
#pragma unroll
    for (int t = 0; t < 4; t++) {
      af[t]  = *(const bf16x8*)(As + (wr * 64 + t * 16 + l15) * 32 + quad * 8);
      bfr[t] = *(const bf16x8*)(Bs + (wc * 64 + t * 16 + l15) * 32 + quad * 8);
    }
#pragma unroll
    for (int mt = 0; mt < 4; mt++)
#pragma unroll
      for (int nt = 0; nt < 4; nt++)
        acc[mt][nt] = __builtin_amdgcn_mfma_f32_16x16x32_bf16(af[mt], bfr[nt], acc[mt][nt], 0, 0, 0);
  }
  // C layout: col=lane&15, row=quad*4+reg
#pragma unroll
  for (int nt = 0; nt < 4; nt++) {
    int gn = n0 + wc * 64 + nt * 16 + l15;
    int which = gn >> 10;   // 0=Q, 1=K, 2=V (uniform across lanes per nt)
    int rem = gn & 1023;
    int hh = rem >> 6, dd = rem & 63;
    if (which == 2) {
      // V transposed: Vt[b][h][dd][s], r-dim is consecutive s -> 8B vector store
#pragma unroll
      for (int mt = 0; mt < 4; mt++) {
        int gm0 = m0 + wr * 64 + mt * 16 + quad * 4;
        int b = gm0 >> 11, s = gm0 & 2047;
        bf16x4 o;
#pragma unroll
        for (int r = 0; r < 4; r++) o[r] = (bf16_t)acc[mt][nt][r];
        *(bf16x4*)(Vt + ((size_t)((b << 4) + hh) * 64 + dd) * 2048 + s) = o;
      }
    } else {
      bf16_t* dst = (which == 0) ? Qb : Kb;
      float scl = (which == 0) ? QSCALE : 1.0f;
#pragma unroll
      for (int mt = 0; mt < 4; mt++) {
#pragma unroll
        for (int r = 0; r < 4; r++) {
          int gm = m0 + wr * 64 + mt * 16 + quad * 4 + r;
          int b = gm >> 11, s = gm & 2047;
          dst[((size_t)((b << 4) + hh) * 2048 + s) * 64 + dd] = (bf16_t)(acc[mt][nt][r] * scl);
        }
      }
    }
  }
}

// pack two f32 into one u32 of 2 bf16
__device__ inline unsigned pack_bf16x2(float a, float b) {
  unsigned short lo = __builtin_bit_cast(unsigned short, (bf16_t)a);
  unsigned short hi = __builtin_bit_cast(unsigned short, (bf16_t)b);
  return (unsigned)lo | ((unsigned)hi << 16);
}

// ---------------- Flash attention, causal, no-max softmax, in-register P ----------------
// Structure: 1024 blocks = 64 bh x 16 Q-tiles, bh in low 6 bits (XCD L2 affinity),
// balanced qb perm; KVBLK=64, LDS 32 KB, 4 blocks/CU; swapped QK^T with
// sigma-permuted K rows; scalar L tree (r6).
// r5-fusion x r6-scalar-L combo: both 32-k bodies of a full 64-k iteration run in
// ONE scheduling region: QK b0 (split 2-chains, critical head) and QK b1 (single
// 4-chain, only 16 regs live) issue back-to-back, so SM b0's VALU runs while b1's
// MFMA chain drains and SM b1 hides under PV b0. r5's spill came from +16 AGPR Lacc
// and +16 dual-split b1 — both now removed; peak regs ~120 < 128 cap.
__global__ __launch_bounds__(256, 4) void attn_kernel(
    const bf16_t* __restrict__ Qg_, const bf16_t* __restrict__ Kg_,
    const bf16_t* __restrict__ Vtg_, bf16_t* __restrict__ ctx) {
  __shared__ __align__(16) bf16_t Ksm[2][64 * 64];  // [k][d], 16B slots XOR row&7  (8 KB each)
  __shared__ __align__(16) bf16_t Vsm[2][64 * 64];  // [d][s], 16B slots XOR d&7    (8 KB each)
  __shared__ float Lsh[128];                        // per-wave L redistribution
  const int tid = threadIdx.x;
  const int lane = tid & 63, w = tid >> 6;
  const int l31 = lane & 31, hl = lane >> 5;
  // sigma: swap bits 2 and 3 of l31 — K A-operand row permutation
  const int krow = (l31 & 0x13) | ((l31 & 4) << 1) | ((l31 & 8) >> 1);

  const int bh = blockIdx.x & 63;          // low bits -> XCD = bh%8
  const int g = blockIdx.x >> 6;           // 0..15
  const int gr = g >> 2, gc = g & 3;
  const int qb = (gr == 0) ? (15 - gc) : (gr == 1) ? (8 + gc) : (gr == 2) ? (7 - gc) : gc;
  const int b = bh >> 4, h = bh & 15;
  const size_t base = (size_t)bh * 2048 * 64;
  const bf16_t* Qg = Qg_ + base;
  const bf16_t* Kg = Kg_ + base;
  const bf16_t* Vtg = Vtg_ + base;  // [d][s]

  int kadr[4];
#pragma unroll
  for (int kk = 0; kk < 4; kk++)
    kadr[kk] = (krow * 8 + ((kk * 2 + hl) ^ (krow & 7))) * 8;
  int vadr[2];
#pragma unroll
  for (int nv = 0; nv < 2; nv++) {
    const int dr = nv * 32 + l31;
    vadr[nv] = (dr * 8 + (hl ^ (dr & 7))) * 8;
  }

  auto stage_kv = [&](int bb, int jn) {
#pragma unroll
    for (int i = 0; i < 2; i++) {
      int slot = i * 256 + tid;                       // 512 16B slots = 64x64 bf16
      int row = slot >> 3, c = (slot & 7) ^ (row & 7);
      __builtin_amdgcn_global_load_lds(AS1(Kg + ((size_t)jn * 64 + row) * 64 + c * 8),
                                       AS3(&Ksm[bb][0] + slot * 8), 16, 0, 0);
    }
#pragma unroll
    for (int i = 0; i < 2; i++) {
      int slot = i * 256 + tid;                       // 512 16B slots = 64x64 bf16
      int d = slot >> 3, c = (slot & 7) ^ (d & 7);
      __builtin_amdgcn_global_load_lds(AS1(Vtg + (size_t)d * 2048 + jn * 64 + c * 8),
                                       AS3(&Vsm[bb][0] + slot * 8), 16, 0, 0);
    }
  };

  f32x16 zc;
#pragma unroll
  for (int e = 0; e < 16; e++) zc[e] = 0.f;

  const int J = 2 * (qb + 1);              // 64-wide KV iters
  const int qrel = qb * 128 + w * 32;      // wave's first q row (global)
  const int qg = qrel + l31;               // this lane's q-row (softmax axis)

  bf16x8 aq[4];
#pragma unroll
  for (int kk = 0; kk < 4; kk++)
    aq[kk] = *(const bf16x8*)(Qg + (size_t)qg * 64 + kk * 16 + hl * 8);

  f32x16 Oacc[2];
#pragma unroll
  for (int e = 0; e < 16; e++) { Oacc[0][e] = 0.f; Oacc[1][e] = 0.f; }
  float Lpart = 0.f;

  int cur = 0;
  stage_kv(0, 0);

  for (int j = 0; j < J; j++) {
    asm volatile("s_waitcnt vmcnt(0)" ::: "memory");
    __syncthreads();
    if (j + 1 < J) stage_kv(cur ^ 1, j + 1);  // flies during compute

    const bf16_t* Kb = &Ksm[cur][0];
    const bf16_t* Vb = &Vsm[cur][0];
    const int k0 = j * 64;

    // softmax+pack: x -> p[], Lpart, pa0/pa1 (all in-register, sigma layout)
    auto smpack = [&](const f32x16& x0, const f32x16& x1, bool masked,
                      bf16x8& pa0, bf16x8& pa1) {
      float p[16];
      if (masked) {
#pragma unroll
        for (int r = 0; r < 16; r++) {
          const int koff = hl * 8 + (r & 7) + 16 * (r >> 3);
          p[r] = (koff > l31) ? 0.f : __builtin_exp2f(x0[r] + x1[r]);
        }
      } else {
#pragma unroll
        for (int r = 0; r < 16; r++) p[r] = __builtin_exp2f(x0[r] + x1[r]);
      }
      {
        float a0s = p[0] + p[1], a1s = p[2] + p[3], a2s = p[4] + p[5], a3s = p[6] + p[7];
        float a4s = p[8] + p[9], a5s = p[10] + p[11], a6s = p[12] + p[13], a7s = p[14] + p[15];
        Lpart += ((a0s + a1s) + (a2s + a3s)) + ((a4s + a5s) + (a6s + a7s));
      }
      u32x4 w0, w1;
      w0[0] = pack_bf16x2(p[0], p[1]);   w0[1] = pack_bf16x2(p[2], p[3]);
      w0[2] = pack_bf16x2(p[4], p[5]);   w0[3] = pack_bf16x2(p[6], p[7]);
      w1[0] = pack_bf16x2(p[8], p[9]);   w1[1] = pack_bf16x2(p[10], p[11]);
      w1[2] = pack_bf16x2(p[12], p[13]); w1[3] = pack_bf16x2(p[14], p[15]);
      pa0 = __builtin_bit_cast(bf16x8, w0);
      pa1 = __builtin_bit_cast(bf16x8, w1);
    };
    auto pv = [&](int nt, bf16x8 pa0, bf16x8 pa1) {
      __builtin_amdgcn_s_setprio(1);
#pragma unroll
      for (int nv = 0; nv < 2; nv++) {
        bf16x8 bv0 = *(const bf16x8*)(Vb + (vadr[nv] ^ ((nt * 4 + 0) * 8)));
        Oacc[nv] = __builtin_amdgcn_mfma_f32_32x32x16_bf16(pa0, bv0, Oacc[nv], 0, 0, 0);
        bf16x8 bv1 = *(const bf16x8*)(Vb + (vadr[nv] ^ ((nt * 4 + 2) * 8)));
        Oacc[nv] = __builtin_amdgcn_mfma_f32_32x32x16_bf16(pa1, bv1, Oacc[nv], 0, 0, 0);
      }
      __builtin_amdgcn_s_setprio(0);
    };

    const bool a1 = (k0 + 32 <= qrel);
    if (a1) {
      // FUSED full iteration: b0 never masked (k0 < qrel); b1 masked iff k0+32==qrel.
      __builtin_amdgcn_s_setprio(1);
      bf16x8 k00 = *(const bf16x8*)(Kb + kadr[0]);
      bf16x8 k01 = *(const bf16x8*)(Kb + kadr[1]);
      bf16x8 k02 = *(const bf16x8*)(Kb + kadr[2]);
      bf16x8 k03 = *(const bf16x8*)(Kb + kadr[3]);
      bf16x8 k10 = *(const bf16x8*)(Kb + 2048 + kadr[0]);
      bf16x8 k11 = *(const bf16x8*)(Kb + 2048 + kadr[1]);
      bf16x8 k12 = *(const bf16x8*)(Kb + 2048 + kadr[2]);
      bf16x8 k13 = *(const bf16x8*)(Kb + 2048 + kadr[3]);
      // b0: split 2-chains (critical-path head)
      f32x16 s0a = __builtin_amdgcn_mfma_f32_32x32x16_bf16(k00, aq[0], zc, 0, 0, 0);
      f32x16 s0b = __builtin_amdgcn_mfma_f32_32x32x16_bf16(k01, aq[1], zc, 0, 0, 0);
      s0a = __builtin_amdgcn_mfma_f32_32x32x16_bf16(k02, aq[2], s0a, 0, 0, 0);
      s0b = __builtin_amdgcn_mfma_f32_32x32x16_bf16(k03, aq[3], s0b, 0, 0, 0);
      // b1: single 4-chain (latency hidden under SM b0; only 16 regs live)
      f32x16 s1 = __builtin_amdgcn_mfma_f32_32x32x16_bf16(k10, aq[0], zc, 0, 0, 0);
      s1 = __builtin_amdgcn_mfma_f32_32x32x16_bf16(k11, aq[1], s1, 0, 0, 0);
      s1 = __builtin_amdgcn_mfma_f32_32x32x16_bf16(k12, aq[2], s1, 0, 0, 0);
      s1 = __builtin_amdgcn_mfma_f32_32x32x16_bf16(k13, aq[3], s1, 0, 0, 0);
      __builtin_amdgcn_s_setprio(0);

      bf16x8 pa0, pa1;
      smpack(s0a, s0b, false, pa0, pa1);   // VALU under b1's MFMA drain
      pv(0, pa0, pa1);
      smpack(s1, zc, k0 + 32 == qrel, pa0, pa1);  // under PV b0's accumulator tail
      pv(1, pa0, pa1);
    } else if (k0 <= qrel) {
      // single-body tail: k0 == qrel -> masked
      __builtin_amdgcn_s_setprio(1);
      bf16x8 k00 = *(const bf16x8*)(Kb + kadr[0]);
      bf16x8 k01 = *(const bf16x8*)(Kb + kadr[1]);
      bf16x8 k02 = *(const bf16x8*)(Kb + kadr[2]);
      bf16x8 k03 = *(const bf16x8*)(Kb + kadr[3]);
      f32x16 s0a = __builtin_amdgcn_mfma_f32_32x32x16_bf16(k00, aq[0], zc, 0, 0, 0);
      f32x16 s0b = __builtin_amdgcn_mfma_f32_32x32x16_bf16(k01, aq[1], zc, 0, 0, 0);
      s0a = __builtin_amdgcn_mfma_f32_32x32x16_bf16(k02, aq[2], s0a, 0, 0, 0);
      s0b = __builtin_amdgcn_mfma_f32_32x32x16_bf16(k03, aq[3], s0b, 0, 0, 0);
      __builtin_amdgcn_s_setprio(0);
      bf16x8 pa0, pa1;
      smpack(s0a, s0b, true, pa0, pa1);
      pv(0, pa0, pa1);
    }
    cur ^= 1;
  }

  // epilogue: L for q=l31 lives per-lane; O rows are crow(r,hl) -> redistribute via
  // tiny wave-private LDS (broadcast reads are free)
  float Lf = Lpart + __shfl_xor(Lpart, 32, 64);
  if (hl == 0) Lsh[w * 32 + l31] = Lf;
  asm volatile("s_waitcnt lgkmcnt(0)" ::: "memory");  // same-wave ds_write -> ds_read
#pragma unroll
  for (int r = 0; r < 16; r++) {
    const int crow = (r & 3) + 8 * (r >> 2) + 4 * hl;
    const float rl = __builtin_amdgcn_rcpf(Lsh[w * 32 + crow]);
    const int qrow = qb * 128 + w * 32 + crow;
#pragma unroll
    for (int nv = 0; nv < 2; nv++)
      ctx[((size_t)b * 2048 + qrow) * 1024 + h * 64 + nv * 32 + l31] =
          (bf16_t)(Oacc[nv][r] * rl);
  }
}

// ---------------- out proj: out[8192,1024] = ctx @ Wout^T + b ----------------
__global__ __launch_bounds__(256) void gemm_out_kernel(
    const bf16_t* __restrict__ A, const bf16_t* __restrict__ Bt,
    const float* __restrict__ bias, float* __restrict__ out) {
  __shared__ __align__(16) bf16_t As[128 * 32];
  __shared__ __align__(16) bf16_t Bs[128 * 32];
  const int tid = threadIdx.x;
  const int lane = tid & 63, wave = tid >> 6;
  const int quad = lane >> 4, l15 = lane & 15;
  const int wr = wave >> 1, wc = wave & 1;
  const int m0 = blockIdx.x * 128, n0 = blockIdx.y * 128;
  f32x4 acc[4][4];
  const f32x4 vzero = {0.f, 0.f, 0.f, 0.f};
#pragma unroll
  for (int i = 0; i < 4; i++)
#pragma unroll
    for (int j = 0; j < 4; j++) acc[i][j] = vzero;

  for (int kb = 0; kb < 1024; kb += 32) {
    __syncthreads();
#pragma unroll
    for (int i = 0; i < 2; i++) {
      int c = i * 256 + tid;
      int row = c >> 2, kc = c & 3;
      __builtin_amdgcn_global_load_lds(AS1(A + (size_t)(m0 + row) * 1024 + kb + kc * 8),
                                       AS3(As + c * 8), 16, 0, 0);
    }
#pragma unroll
    for (int i = 0; i < 2; i++) {
      int c = i * 256 + tid;
      int row = c >> 2, kc = c & 3;
      __builtin_amdgcn_global_load_lds(AS1(Bt + (size_t)(n0 + row) * 1024 + kb + kc * 8),
                                       AS3(Bs + c * 8), 16, 0, 0);
    }
    __builtin_amdgcn_s_waitcnt(0);
    __syncthreads();
    bf16x8 af[4], bfr[4];
#pragma unroll
    for (int t = 0; t < 4; t++) {
      af[t]  = *(const bf16x8*)(As + (wr * 64 + t * 16 + l15) * 32 + quad * 8);
      bfr[t] = *(const bf16x8*)(Bs + (wc * 64 + t * 16 + l15) * 32 + quad * 8);
    }
#pragma unroll
    for (int mt = 0; mt < 4; mt++)
#pragma unroll
      for (int nt = 0; nt < 4; nt++)
        acc[mt][nt] = __builtin_amdgcn_mfma_f32_16x16x32_bf16(af[mt], bfr[nt], acc[mt][nt], 0, 0, 0);
  }
#pragma unroll
  for (int nt = 0; nt < 4; nt++) {
    int gn = n0 + wc * 64 + nt * 16 + l15;
    float bv = bias[gn];
#pragma unroll
    for (int mt = 0; mt < 4; mt++) {
#pragma unroll
      for (int r = 0; r < 4; r++) {
        int gm = m0 + wr * 64 + mt * 16 + quad * 4 + r;
        out[(size_t)gm * 1024 + gn] = acc[mt][nt][r] + bv;
      }
    }
  }
}

extern "C" void kernel_launch(void* const* d_in, const int* in_sizes, int n_in,
                              void* d_out, int out_size, void* d_ws, size_t ws_size,
                              hipStream_t stream) {
  (void)in_sizes; (void)n_in; (void)out_size; (void)ws_size;
  const float* X     = (const float*)d_in[0];  // [4,2048,1024]
  const float* W_qkv = (const float*)d_in[1];  // [1024,3072]
  const float* W_out = (const float*)d_in[2];  // [1024,1024]
  const float* b_out = (const float*)d_in[3];  // [1024]
  float* out = (float*)d_out;                  // [4,2048,1024] fp32

  char* ws = (char*)d_ws;
  bf16_t* Xb    = (bf16_t*)(ws);               // 16 MB
  bf16_t* Wqkvt = (bf16_t*)(ws + 16777216);    // 6 MB   [3072][1024]
  bf16_t* Woutt = (bf16_t*)(ws + 23068672);    // 2 MB   [1024][1024]
  bf16_t* Qb    = (bf16_t*)(ws + 25165824);    // 16 MB  [b,h,s,d]
  bf16_t* Kb    = (bf16_t*)(ws + 41943040);    // 16 MB  [b,h,s,d]
  bf16_t* Vt    = (bf16_t*)(ws + 58720256);    // 16 MB  [b,h,d,s] (written directly by GEMM)
  bf16_t* ctx   = (bf16_t*)(ws + 75497472);    // 16 MB  [b,s,1024]

  prep_kernel<<<12288, 256, 0, stream>>>(X, Xb, W_qkv, Wqkvt, W_out, Woutt);
  gemm_qkv_kernel<<<dim3(64, 24), 256, 0, stream>>>(Xb, Wqkvt, Qb, Kb, Vt);
  attn_kernel<<<dim3(1024), 256, 0, stream>>>(Qb, Kb, Vt, ctx);
  gemm_out_kernel<<<dim3(64, 8), 256, 0, stream>>>(ctx, Woutt, b_out, out);
}

// Round 11
// 249.593 us; speedup vs baseline: 1.4570x; 1.4570x over previous
//
#include <hip/hip_runtime.h>
#include <hip/hip_bf16.h>

typedef __bf16 bf16_t;
typedef __bf16 bf16x8 __attribute__((ext_vector_type(8)));
typedef __bf16 bf16x4 __attribute__((ext_vector_type(4)));
typedef float f32x4 __attribute__((ext_vector_type(4)));
typedef float f32x16 __attribute__((ext_vector_type(16)));
typedef unsigned int u32x4 __attribute__((ext_vector_type(4)));

#define AS1(p) ((const __attribute__((address_space(1))) void*)(p))
#define AS3(p) ((__attribute__((address_space(3))) void*)(p))

// scale = HEAD_DIM^-0.5 * log2(e), folded into Q at QKV-GEMM epilogue
#define QSCALE 0.1803368801111204f

// ---------------- fused prep: cast X + transpose/cast both W (one launch) ----------------
__global__ __launch_bounds__(256) void prep_kernel(
    const float* __restrict__ X, bf16_t* __restrict__ Xb,
    const float* __restrict__ Wqkv, bf16_t* __restrict__ Wqkvt,
    const float* __restrict__ Wout, bf16_t* __restrict__ Woutt) {
  __shared__ float tile[32][33];
  int bid = blockIdx.x;
  if (bid < 8192) {
    int i = (bid * 256 + threadIdx.x) * 4;
    float4 v = *(const float4*)(X + i);
    bf16x4 o;
    o[0] = (bf16_t)v.x; o[1] = (bf16_t)v.y; o[2] = (bf16_t)v.z; o[3] = (bf16_t)v.w;
    *(bf16x4*)(Xb + i) = o;
    return;
  }
  bid -= 8192;
  const float* W; bf16_t* Wt; int N, bx, by;
  if (bid < 3072) { W = Wqkv; Wt = Wqkvt; N = 3072; bx = bid % 96; by = bid / 96; }
  else { bid -= 3072; W = Wout; Wt = Woutt; N = 1024; bx = bid & 31; by = bid >> 5; }
  const int K = 1024;
  int tx = threadIdx.x & 31, ty = threadIdx.x >> 5;
  int n0 = bx * 32, k0 = by * 32;
  for (int r = ty; r < 32; r += 8)
    tile[r][tx] = W[(size_t)(k0 + r) * N + n0 + tx];
  __syncthreads();
  for (int r = ty; r < 32; r += 8)
    Wt[(size_t)(n0 + r) * K + k0 + tx] = (bf16_t)tile[tx][r];
}

// ---------------- QKV GEMM: C[8192,3072] = Xb[8192,1024] @ Wt[3072,1024]^T ----------------
// 1D grid (1536) with XCD-band swizzle (T1): bid = a + 8b + 64c -> m-tile 8a+b,
// n-tile c. XCD = bid%8 = a owns an 8-wide m-band: its A working set (2 MB) stays
// L2-resident; B streams once via L3. Bijective remap (a<8, b<8, c<24).
__global__ __launch_bounds__(256) void gemm_qkv_kernel(
    const bf16_t* __restrict__ A, const bf16_t* __restrict__ Bt,
    bf16_t* __restrict__ Qb, bf16_t* __restrict__ Kb, bf16_t* __restrict__ Vt) {
  __shared__ __align__(16) bf16_t As[128 * 32];
  __shared__ __align__(16) bf16_t Bs[128 * 32];
  const int tid = threadIdx.x;
  const int lane = tid & 63, wave = tid >> 6;
  const int quad = lane >> 4, l15 = lane & 15;
  const int wr = wave >> 1, wc = wave & 1;
  const int bid = blockIdx.x;
  const int mt_ = (bid & 7) * 8 + ((bid >> 3) & 7);  // m-tile 0..63
  const int nt_ = bid >> 6;                          // n-tile 0..23
  const int m0 = mt_ * 128, n0 = nt_ * 128;
  f32x4 acc[4][4];
  const f32x4 vzero = {0.f, 0.f, 0.f, 0.f};
#pragma unroll
  for (int i = 0; i < 4; i++)
#pragma unroll
    for (int j = 0; j < 4; j++) acc[i][j] = vzero;

  for (int kb = 0; kb < 1024; kb += 32) {
    __syncthreads();
#pragma unroll
    for (int i = 0; i < 2; i++) {
      int c = i * 256 + tid;
      int row = c >> 2, kc = c & 3;
      __builtin_amdgcn_global_load_lds(AS1(A + (size_t)(m0 + row) * 1024 + kb + kc * 8),
                                       AS3(As + c * 8), 16, 0, 0);
    }
#pragma unroll
    for (int i = 0; i < 2; i++) {
      int c = i * 256 + tid;
      int row = c >> 2, kc = c & 3;
      __builtin_amdgcn_global_load_lds(AS1(Bt + (size_t)(n0 + row) * 1024 + kb + kc * 8),
                                       AS3(Bs + c * 8), 16, 0, 0);
    }
    __builtin_amdgcn_s_waitcnt(0);
    __syncthreads();
    bf16x8 af[4], bfr[4];
#pragma unroll
    for (int t = 0; t < 4; t++) {
      af[t]  = *(const bf16x8*)(As + (wr * 64 + t * 16 + l15) * 32 + quad * 8);
      bfr[t] = *(const bf16x8*)(Bs + (wc * 64 + t * 16 + l15) * 32 + quad * 8);
    }
#pragma unroll
    for (int mt = 0; mt < 4; mt++)
#pragma unroll
      for (int nt = 0; nt < 4; nt++)
        acc[mt][nt] = __builtin_amdgcn_mfma_f32_16x16x32_bf16(af[mt], bfr[nt], acc[mt][nt], 0, 0, 0);
  }
  // C layout: col=lane&15, row=quad*4+reg
#pragma unroll
  for (int nt = 0; nt < 4; nt++) {
    int gn = n0 + wc * 64 + nt * 16 + l15;
    int which = gn >> 10;   // 0=Q, 1=K, 2=V (uniform across lanes per nt)
    int rem = gn & 1023;
    int hh = rem >> 6, dd = rem & 63;
    if (which == 2) {
      // V transposed: Vt[b][h][dd][s], r-dim is consecutive s -> 8B vector store
#pragma unroll
      for (int mt = 0; mt < 4; mt++) {
        int gm0 = m0 + wr * 64 + mt * 16 + quad * 4;
        int b = gm0 >> 11, s = gm0 & 2047;
        bf16x4 o;
#pragma unroll
        for (int r = 0; r < 4; r++) o[r] = (bf16_t)acc[mt][nt][r];
        *(bf16x4*)(Vt + ((size_t)((b << 4) + hh) * 64 + dd) * 2048 + s) = o;
      }
    } else {
      bf16_t* dst = (which == 0) ? Qb : Kb;
      float scl = (which == 0) ? QSCALE : 1.0f;
#pragma unroll
      for (int mt = 0; mt < 4; mt++) {
#pragma unroll
        for (int r = 0; r < 4; r++) {
          int gm = m0 + wr * 64 + mt * 16 + quad * 4 + r;
          int b = gm >> 11, s = gm & 2047;
          dst[((size_t)((b << 4) + hh) * 2048 + s) * 64 + dd] = (bf16_t)(acc[mt][nt][r] * scl);
        }
      }
    }
  }
}

// pack two f32 into one u32 of 2 bf16
__device__ inline unsigned pack_bf16x2(float a, float b) {
  unsigned short lo = __builtin_bit_cast(unsigned short, (bf16_t)a);
  unsigned short hi = __builtin_bit_cast(unsigned short, (bf16_t)b);
  return (unsigned)lo | ((unsigned)hi << 16);
}

// ---------------- Flash attention, causal, no-max softmax, in-register P ----------------
// EXACT r8-measured version (74.4 us, WRITE 16 MB). Fusion variants r5/r10 both
// spilled (42 MB / 516 MB scratch): at 4 blocks/CU this datapath cannot hold >2
// f32x16 accumulators across a region — do NOT re-fuse. Structure: 1024 blocks =
// 64 bh x 16 Q-tiles, bh in low 6 bits (XCD L2 affinity), balanced qb perm;
// KVBLK=64, LDS 32 KB, 4 blocks/CU; sigma-permuted swapped QK^T; scalar L tree;
// QK split into two independent 2-chains.
__global__ __launch_bounds__(256, 4) void attn_kernel(
    const bf16_t* __restrict__ Qg_, const bf16_t* __restrict__ Kg_,
    const bf16_t* __restrict__ Vtg_, bf16_t* __restrict__ ctx) {
  __shared__ __align__(16) bf16_t Ksm[2][64 * 64];  // [k][d], 16B slots XOR row&7  (8 KB each)
  __shared__ __align__(16) bf16_t Vsm[2][64 * 64];  // [d][s], 16B slots XOR d&7    (8 KB each)
  __shared__ float Lsh[128];                        // per-wave L redistribution
  const int tid = threadIdx.x;
  const int lane = tid & 63, w = tid >> 6;
  const int l31 = lane & 31, hl = lane >> 5;
  // sigma: swap bits 2 and 3 of l31 — K A-operand row permutation
  const int krow = (l31 & 0x13) | ((l31 & 4) << 1) | ((l31 & 8) >> 1);

  const int bh = blockIdx.x & 63;          // low bits -> XCD = bh%8
  const int g = blockIdx.x >> 6;           // 0..15
  const int gr = g >> 2, gc = g & 3;
  const int qb = (gr == 0) ? (15 - gc) : (gr == 1) ? (8 + gc) : (gr == 2) ? (7 - gc) : gc;
  const int b = bh >> 4, h = bh & 15;
  const size_t base = (size_t)bh * 2048 * 64;
  const bf16_t* Qg = Qg_ + base;
  const bf16_t* Kg = Kg_ + base;
  const bf16_t* Vtg = Vtg_ + base;  // [d][s]

  int kadr[4];
#pragma unroll
  for (int kk = 0; kk < 4; kk++)
    kadr[kk] = (krow * 8 + ((kk * 2 + hl) ^ (krow & 7))) * 8;
  int vadr[2];
#pragma unroll
  for (int nv = 0; nv < 2; nv++) {
    const int dr = nv * 32 + l31;
    vadr[nv] = (dr * 8 + (hl ^ (dr & 7))) * 8;
  }

  auto stage_kv = [&](int bb, int jn) {
#pragma unroll
    for (int i = 0; i < 2; i++) {
      int slot = i * 256 + tid;                       // 512 16B slots = 64x64 bf16
      int row = slot >> 3, c = (slot & 7) ^ (row & 7);
      __builtin_amdgcn_global_load_lds(AS1(Kg + ((size_t)jn * 64 + row) * 64 + c * 8),
                                       AS3(&Ksm[bb][0] + slot * 8), 16, 0, 0);
    }
#pragma unroll
    for (int i = 0; i < 2; i++) {
      int slot = i * 256 + tid;                       // 512 16B slots = 64x64 bf16
      int d = slot >> 3, c = (slot & 7) ^ (d & 7);
      __builtin_amdgcn_global_load_lds(AS1(Vtg + (size_t)d * 2048 + jn * 64 + c * 8),
                                       AS3(&Vsm[bb][0] + slot * 8), 16, 0, 0);
    }
  };

  f32x16 zc;
#pragma unroll
  for (int e = 0; e < 16; e++) zc[e] = 0.f;

  const int J = 2 * (qb + 1);              // 64-wide KV iters
  const int qrel = qb * 128 + w * 32;      // wave's first q row (global)
  const int qg = qrel + l31;               // this lane's q-row (softmax axis)

  bf16x8 aq[4];
#pragma unroll
  for (int kk = 0; kk < 4; kk++)
    aq[kk] = *(const bf16x8*)(Qg + (size_t)qg * 64 + kk * 16 + hl * 8);

  f32x16 Oacc[2];
#pragma unroll
  for (int e = 0; e < 16; e++) { Oacc[0][e] = 0.f; Oacc[1][e] = 0.f; }
  float Lpart = 0.f;

  int cur = 0;
  stage_kv(0, 0);

  for (int j = 0; j < J; j++) {
    asm volatile("s_waitcnt vmcnt(0)" ::: "memory");
    __syncthreads();
    if (j + 1 < J) stage_kv(cur ^ 1, j + 1);  // flies during compute

    const bf16_t* Kb = &Ksm[cur][0];
    const bf16_t* Vb = &Vsm[cur][0];
    const int k0 = j * 64;

    auto nt_body = [&](int nt, bool masked) {
      // S^T[k][q=l31] = sum_d K[k][d] * Q[q][d], k rows sigma-permuted.
      // Two independent 2-chains (sa: kk 0,2 / sb: kk 1,3) halve the dep latency.
      __builtin_amdgcn_s_setprio(1);
      bf16x8 a0 = *(const bf16x8*)(Kb + nt * 2048 + kadr[0]);
      bf16x8 a1 = *(const bf16x8*)(Kb + nt * 2048 + kadr[1]);
      f32x16 sa = __builtin_amdgcn_mfma_f32_32x32x16_bf16(a0, aq[0], zc, 0, 0, 0);
      f32x16 sb = __builtin_amdgcn_mfma_f32_32x32x16_bf16(a1, aq[1], zc, 0, 0, 0);
      bf16x8 a2 = *(const bf16x8*)(Kb + nt * 2048 + kadr[2]);
      bf16x8 a3 = *(const bf16x8*)(Kb + nt * 2048 + kadr[3]);
      sa = __builtin_amdgcn_mfma_f32_32x32x16_bf16(a2, aq[2], sa, 0, 0, 0);
      sb = __builtin_amdgcn_mfma_f32_32x32x16_bf16(a3, aq[3], sb, 0, 0, 0);
      __builtin_amdgcn_s_setprio(0);

      // lane's 16 values sit at k-offs hl*8 + (r&7) + 16*(r>>3)  (thanks to sigma)
      float p[16];
#pragma unroll
      for (int r = 0; r < 16; r++) {
        const int koff = hl * 8 + (r & 7) + 16 * (r >> 3);
        const float x = sa[r] + sb[r];
        p[r] = (masked && (koff > l31)) ? 0.f : __builtin_exp2f(x);
      }

      // L row-sum: in-register tree (partner half folded once at the end)
      {
        float a0s = p[0] + p[1], a1s = p[2] + p[3], a2s = p[4] + p[5], a3s = p[6] + p[7];
        float a4s = p[8] + p[9], a5s = p[10] + p[11], a6s = p[12] + p[13], a7s = p[14] + p[15];
        Lpart += ((a0s + a1s) + (a2s + a3s)) + ((a4s + a5s) + (a6s + a7s));
      }

      // P bf16 A-fragments, directly in-lane (no cross-lane ops)
      u32x4 w0, w1;
      w0[0] = pack_bf16x2(p[0], p[1]);   w0[1] = pack_bf16x2(p[2], p[3]);
      w0[2] = pack_bf16x2(p[4], p[5]);   w0[3] = pack_bf16x2(p[6], p[7]);
      w1[0] = pack_bf16x2(p[8], p[9]);   w1[1] = pack_bf16x2(p[10], p[11]);
      w1[2] = pack_bf16x2(p[12], p[13]); w1[3] = pack_bf16x2(p[14], p[15]);
      bf16x8 pa0 = __builtin_bit_cast(bf16x8, w0);  // k-offs nt*32 + 0..15
      bf16x8 pa1 = __builtin_bit_cast(bf16x8, w1);  // k-offs nt*32 + 16..31

      __builtin_amdgcn_s_setprio(1);
      // O += P @ V  (B-operand: n=l31=dv, k=hl*8+e along s)
#pragma unroll
      for (int nv = 0; nv < 2; nv++) {
        bf16x8 bv0 = *(const bf16x8*)(Vb + (vadr[nv] ^ ((nt * 4 + 0) * 8)));
        Oacc[nv] = __builtin_amdgcn_mfma_f32_32x32x16_bf16(pa0, bv0, Oacc[nv], 0, 0, 0);
        bf16x8 bv1 = *(const bf16x8*)(Vb + (vadr[nv] ^ ((nt * 4 + 2) * 8)));
        Oacc[nv] = __builtin_amdgcn_mfma_f32_32x32x16_bf16(pa1, bv1, Oacc[nv], 0, 0, 0);
      }
      __builtin_amdgcn_s_setprio(0);
    };

#pragma unroll
    for (int nt = 0; nt < 2; nt++) {
      const int kk0 = k0 + nt * 32;
      if (kk0 <= qrel) nt_body(nt, kk0 == qrel);  // kk0 > qrel: fully masked -> skip
    }
    cur ^= 1;
  }

  // epilogue: L for q=l31 lives per-lane; O rows are crow(r,hl) -> redistribute via
  // tiny wave-private LDS (broadcast reads are free)
  float Lf = Lpart + __shfl_xor(Lpart, 32, 64);
  if (hl == 0) Lsh[w * 32 + l31] = Lf;
  asm volatile("s_waitcnt lgkmcnt(0)" ::: "memory");  // same-wave ds_write -> ds_read
#pragma unroll
  for (int r = 0; r < 16; r++) {
    const int crow = (r & 3) + 8 * (r >> 2) + 4 * hl;
    const float rl = __builtin_amdgcn_rcpf(Lsh[w * 32 + crow]);
    const int qrow = qb * 128 + w * 32 + crow;
#pragma unroll
    for (int nv = 0; nv < 2; nv++)
      ctx[((size_t)b * 2048 + qrow) * 1024 + h * 64 + nv * 32 + l31] =
          (bf16_t)(Oacc[nv][r] * rl);
  }
}

// ---------------- out proj: out[8192,1024] = ctx @ Wout^T + b ----------------
// 1D grid (512) with the same XCD-band swizzle: m-tile = 8a+b, n-tile = bid>>6.
__global__ __launch_bounds__(256) void gemm_out_kernel(
    const bf16_t* __restrict__ A, const bf16_t* __restrict__ Bt,
    const float* __restrict__ bias, float* __restrict__ out) {
  __shared__ __align__(16) bf16_t As[128 * 32];
  __shared__ __align__(16) bf16_t Bs[128 * 32];
  const int tid = threadIdx.x;
  const int lane = tid & 63, wave = tid >> 6;
  const int quad = lane >> 4, l15 = lane & 15;
  const int wr = wave >> 1, wc = wave & 1;
  const int bid = blockIdx.x;
  const int mt_ = (bid & 7) * 8 + ((bid >> 3) & 7);  // m-tile 0..63
  const int nt_ = bid >> 6;                          // n-tile 0..7
  const int m0 = mt_ * 128, n0 = nt_ * 128;
  f32x4 acc[4][4];
  const f32x4 vzero = {0.f, 0.f, 0.f, 0.f};
#pragma unroll
  for (int i = 0; i < 4; i++)
#pragma unroll
    for (int j = 0; j < 4; j++) acc[i][j] = vzero;

  for (int kb = 0; kb < 1024; kb += 32) {
    __syncthreads();
#pragma unroll
    for (int i = 0; i < 2; i++) {
      int c = i * 256 + tid;
      int row = c >> 2, kc = c & 3;
      __builtin_amdgcn_global_load_lds(AS1(A + (size_t)(m0 + row) * 1024 + kb + kc * 8),
                                       AS3(As + c * 8), 16, 0, 0);
    }
#pragma unroll
    for (int i = 0; i < 2; i++) {
      int c = i * 256 + tid;
      int row = c >> 2, kc = c & 3;
      __builtin_amdgcn_global_load_lds(AS1(Bt + (size_t)(n0 + row) * 1024 + kb + kc * 8),
                                       AS3(Bs + c * 8), 16, 0, 0);
    }
    __builtin_amdgcn_s_waitcnt(0);
    __syncthreads();
    bf16x8 af[4], bfr[4];
#pragma unroll
    for (int t = 0; t < 4; t++) {
      af[t]  = *(const bf16x8*)(As + (wr * 64 + t * 16 + l15) * 32 + quad * 8);
      bfr[t] = *(const bf16x8*)(Bs + (wc * 64 + t * 16 + l15) * 32 + quad * 8);
    }
#pragma unroll
    for (int mt = 0; mt < 4; mt++)
#pragma unroll
      for (int nt = 0; nt < 4; nt++)
        acc[mt][nt] = __builtin_amdgcn_mfma_f32_16x16x32_bf16(af[mt], bfr[nt], acc[mt][nt], 0, 0, 0);
  }
#pragma unroll
  for (int nt = 0; nt < 4; nt++) {
    int gn = n0 + wc * 64 + nt * 16 + l15;
    float bv = bias[gn];
#pragma unroll
    for (int mt = 0; mt < 4; mt++) {
#pragma unroll
      for (int r = 0; r < 4; r++) {
        int gm = m0 + wr * 64 + mt * 16 + quad * 4 + r;
        out[(size_t)gm * 1024 + gn] = acc[mt][nt][r] + bv;
      }
    }
  }
}

extern "C" void kernel_launch(void* const* d_in, const int* in_sizes, int n_in,
                              void* d_out, int out_size, void* d_ws, size_t ws_size,
                              hipStream_t stream) {
  (void)in_sizes; (void)n_in; (void)out_size; (void)ws_size;
  const float* X     = (const float*)d_in[0];  // [4,2048,1024]
  const float* W_qkv = (const float*)d_in[1];  // [1024,3072]
  const float* W_out = (const float*)d_in[2];  // [1024,1024]
  const float* b_out = (const float*)d_in[3];  // [1024]
  float* out = (float*)d_out;                  // [4,2048,1024] fp32

  char* ws = (char*)d_ws;
  bf16_t* Xb    = (bf16_t*)(ws);               // 16 MB
  bf16_t* Wqkvt = (bf16_t*)(ws + 16777216);    // 6 MB   [3072][1024]
  bf16_t* Woutt = (bf16_t*)(ws + 23068672);    // 2 MB   [1024][1024]
  bf16_t* Qb    = (bf16_t*)(ws + 25165824);    // 16 MB  [b,h,s,d]
  bf16_t* Kb    = (bf16_t*)(ws + 41943040);    // 16 MB  [b,h,s,d]
  bf16_t* Vt    = (bf16_t*)(ws + 58720256);    // 16 MB  [b,h,d,s] (written directly by GEMM)
  bf16_t* ctx   = (bf16_t*)(ws + 75497472);    // 16 MB  [b,s,1024]

  prep_kernel<<<12288, 256, 0, stream>>>(X, Xb, W_qkv, Wqkvt, W_out, Woutt);
  gemm_qkv_kernel<<<1536, 256, 0, stream>>>(Xb, Wqkvt, Qb, Kb, Vt);
  attn_kernel<<<dim3(1024), 256, 0, stream>>>(Qb, Kb, Vt, ctx);
  gemm_out_kernel<<<512, 256, 0, stream>>>(ctx, Woutt, b_out, out);
}

// Round 12
// 246.861 us; speedup vs baseline: 1.4732x; 1.0111x over previous
//
#include <hip/hip_runtime.h>
#include <hip/hip_bf16.h>

typedef __bf16 bf16_t;
typedef __bf16 bf16x8 __attribute__((ext_vector_type(8)));
typedef __bf16 bf16x4 __attribute__((ext_vector_type(4)));
typedef float f32x4 __attribute__((ext_vector_type(4)));
typedef float f32x16 __attribute__((ext_vector_type(16)));
typedef unsigned int u32x4 __attribute__((ext_vector_type(4)));

#define AS1(p) ((const __attribute__((address_space(1))) void*)(p))
#define AS3(p) ((__attribute__((address_space(3))) void*)(p))

// scale = HEAD_DIM^-0.5 * log2(e), folded into Q at QKV-GEMM epilogue
#define QSCALE 0.1803368801111204f

// ---------------- fused prep: cast X + transpose/cast both W (one launch) ----------------
__global__ __launch_bounds__(256) void prep_kernel(
    const float* __restrict__ X, bf16_t* __restrict__ Xb,
    const float* __restrict__ Wqkv, bf16_t* __restrict__ Wqkvt,
    const float* __restrict__ Wout, bf16_t* __restrict__ Woutt) {
  __shared__ float tile[32][33];
  int bid = blockIdx.x;
  if (bid < 8192) {
    int i = (bid * 256 + threadIdx.x) * 4;
    float4 v = *(const float4*)(X + i);
    bf16x4 o;
    o[0] = (bf16_t)v.x; o[1] = (bf16_t)v.y; o[2] = (bf16_t)v.z; o[3] = (bf16_t)v.w;
    *(bf16x4*)(Xb + i) = o;
    return;
  }
  bid -= 8192;
  const float* W; bf16_t* Wt; int N, bx, by;
  if (bid < 3072) { W = Wqkv; Wt = Wqkvt; N = 3072; bx = bid % 96; by = bid / 96; }
  else { bid -= 3072; W = Wout; Wt = Woutt; N = 1024; bx = bid & 31; by = bid >> 5; }
  const int K = 1024;
  int tx = threadIdx.x & 31, ty = threadIdx.x >> 5;
  int n0 = bx * 32, k0 = by * 32;
  for (int r = ty; r < 32; r += 8)
    tile[r][tx] = W[(size_t)(k0 + r) * N + n0 + tx];
  __syncthreads();
  for (int r = ty; r < 32; r += 8)
    Wt[(size_t)(n0 + r) * K + k0 + tx] = (bf16_t)tile[tx][r];
}

// ---------------- QKV GEMM: C[8192,3072] = Xb[8192,1024] @ Wt[3072,1024]^T ----------------
// BK=64: one stage + one vmcnt(0) drain + 2 barriers per 64-wide K-step (16 rounds
// vs 32) — per-round fixed costs amortize over 2x MFMA. Single-buffered (r7's dbuf
// regression mechanism absent). [128][64] LDS would be bank-0-only at row stride
// 128B, so staging pre-swizzles the GLOBAL chunk (chunk ^ row&7) with linear LDS
// dest (rule #21, attn-Ksm-verified); ds_read applies the same XOR -> 2-way max.
// XCD-band swizzle (r11): bid = a + 8b + 64c -> m-tile 8a+b, n-tile c.
__global__ __launch_bounds__(256) void gemm_qkv_kernel(
    const bf16_t* __restrict__ A, const bf16_t* __restrict__ Bt,
    bf16_t* __restrict__ Qb, bf16_t* __restrict__ Kb, bf16_t* __restrict__ Vt) {
  __shared__ __align__(16) bf16_t As[128 * 64];
  __shared__ __align__(16) bf16_t Bs[128 * 64];
  const int tid = threadIdx.x;
  const int lane = tid & 63, wave = tid >> 6;
  const int quad = lane >> 4, l15 = lane & 15;
  const int wr = wave >> 1, wc = wave & 1;
  const int bid = blockIdx.x;
  const int mt_ = (bid & 7) * 8 + ((bid >> 3) & 7);  // m-tile 0..63
  const int nt_ = bid >> 6;                          // n-tile 0..23
  const int m0 = mt_ * 128, n0 = nt_ * 128;
  f32x4 acc[4][4];
  const f32x4 vzero = {0.f, 0.f, 0.f, 0.f};
#pragma unroll
  for (int i = 0; i < 4; i++)
#pragma unroll
    for (int j = 0; j < 4; j++) acc[i][j] = vzero;

  for (int kb = 0; kb < 1024; kb += 64) {
    __syncthreads();
#pragma unroll
    for (int i = 0; i < 4; i++) {
      int slot = i * 256 + tid;                 // 1024 slots x 16B = 128 rows x 64 k
      int row = slot >> 3, ch = slot & 7;
      int gch = ch ^ (row & 7);                 // pre-swizzled global chunk
      __builtin_amdgcn_global_load_lds(AS1(A + (size_t)(m0 + row) * 1024 + kb + gch * 8),
                                       AS3(As + slot * 8), 16, 0, 0);
    }
#pragma unroll
    for (int i = 0; i < 4; i++) {
      int slot = i * 256 + tid;
      int row = slot >> 3, ch = slot & 7;
      int gch = ch ^ (row & 7);
      __builtin_amdgcn_global_load_lds(AS1(Bt + (size_t)(n0 + row) * 1024 + kb + gch * 8),
                                       AS3(Bs + slot * 8), 16, 0, 0);
    }
    __builtin_amdgcn_s_waitcnt(0);
    __syncthreads();
#pragma unroll
    for (int ks = 0; ks < 2; ks++) {            // two 32-wide K-substeps
      bf16x8 af[4], bfr[4];
#pragma unroll
      for (int t = 0; t < 4; t++) {
        int ra = wr * 64 + t * 16 + l15;
        af[t]  = *(const bf16x8*)(As + ra * 64 + ((ks * 4 + quad) ^ (ra & 7)) * 8);
        int rb = wc * 64 + t * 16 + l15;
        bfr[t] = *(const bf16x8*)(Bs + rb * 64 + ((ks * 4 + quad) ^ (rb & 7)) * 8);
      }
#pragma unroll
      for (int mt = 0; mt < 4; mt++)
#pragma unroll
        for (int nt = 0; nt < 4; nt++)
          acc[mt][nt] = __builtin_amdgcn_mfma_f32_16x16x32_bf16(af[mt], bfr[nt], acc[mt][nt], 0, 0, 0);
    }
  }
  // C layout: col=lane&15, row=quad*4+reg
#pragma unroll
  for (int nt = 0; nt < 4; nt++) {
    int gn = n0 + wc * 64 + nt * 16 + l15;
    int which = gn >> 10;   // 0=Q, 1=K, 2=V (uniform across lanes per nt)
    int rem = gn & 1023;
    int hh = rem >> 6, dd = rem & 63;
    if (which == 2) {
      // V transposed: Vt[b][h][dd][s], r-dim is consecutive s -> 8B vector store
#pragma unroll
      for (int mt = 0; mt < 4; mt++) {
        int gm0 = m0 + wr * 64 + mt * 16 + quad * 4;
        int b = gm0 >> 11, s = gm0 & 2047;
        bf16x4 o;
#pragma unroll
        for (int r = 0; r < 4; r++) o[r] = (bf16_t)acc[mt][nt][r];
        *(bf16x4*)(Vt + ((size_t)((b << 4) + hh) * 64 + dd) * 2048 + s) = o;
      }
    } else {
      bf16_t* dst = (which == 0) ? Qb : Kb;
      float scl = (which == 0) ? QSCALE : 1.0f;
#pragma unroll
      for (int mt = 0; mt < 4; mt++) {
#pragma unroll
        for (int r = 0; r < 4; r++) {
          int gm = m0 + wr * 64 + mt * 16 + quad * 4 + r;
          int b = gm >> 11, s = gm & 2047;
          dst[((size_t)((b << 4) + hh) * 2048 + s) * 64 + dd] = (bf16_t)(acc[mt][nt][r] * scl);
        }
      }
    }
  }
}

// pack two f32 into one u32 of 2 bf16
__device__ inline unsigned pack_bf16x2(float a, float b) {
  unsigned short lo = __builtin_bit_cast(unsigned short, (bf16_t)a);
  unsigned short hi = __builtin_bit_cast(unsigned short, (bf16_t)b);
  return (unsigned)lo | ((unsigned)hi << 16);
}

// ---------------- Flash attention, causal, no-max softmax, in-register P ----------------
// EXACT r8/r11-measured version (74-77 us band). Fusion variants r5/r10 both spilled
// (42 MB / 516 MB scratch): at 4 blocks/CU this datapath cannot hold >2 f32x16
// accumulators across a region — do NOT re-fuse. Structure: 1024 blocks = 64 bh x
// 16 Q-tiles, bh in low 6 bits (XCD L2 affinity), balanced qb perm; KVBLK=64,
// LDS 32 KB, 4 blocks/CU; sigma-permuted swapped QK^T; scalar L tree; QK split
// into two independent 2-chains.
__global__ __launch_bounds__(256, 4) void attn_kernel(
    const bf16_t* __restrict__ Qg_, const bf16_t* __restrict__ Kg_,
    const bf16_t* __restrict__ Vtg_, bf16_t* __restrict__ ctx) {
  __shared__ __align__(16) bf16_t Ksm[2][64 * 64];  // [k][d], 16B slots XOR row&7  (8 KB each)
  __shared__ __align__(16) bf16_t Vsm[2][64 * 64];  // [d][s], 16B slots XOR d&7    (8 KB each)
  __shared__ float Lsh[128];                        // per-wave L redistribution
  const int tid = threadIdx.x;
  const int lane = tid & 63, w = tid >> 6;
  const int l31 = lane & 31, hl = lane >> 5;
  // sigma: swap bits 2 and 3 of l31 — K A-operand row permutation
  const int krow = (l31 & 0x13) | ((l31 & 4) << 1) | ((l31 & 8) >> 1);

  const int bh = blockIdx.x & 63;          // low bits -> XCD = bh%8
  const int g = blockIdx.x >> 6;           // 0..15
  const int gr = g >> 2, gc = g & 3;
  const int qb = (gr == 0) ? (15 - gc) : (gr == 1) ? (8 + gc) : (gr == 2) ? (7 - gc) : gc;
  const int b = bh >> 4, h = bh & 15;
  const size_t base = (size_t)bh * 2048 * 64;
  const bf16_t* Qg = Qg_ + base;
  const bf16_t* Kg = Kg_ + base;
  const bf16_t* Vtg = Vtg_ + base;  // [d][s]

  int kadr[4];
#pragma unroll
  for (int kk = 0; kk < 4; kk++)
    kadr[kk] = (krow * 8 + ((kk * 2 + hl) ^ (krow & 7))) * 8;
  int vadr[2];
#pragma unroll
  for (int nv = 0; nv < 2; nv++) {
    const int dr = nv * 32 + l31;
    vadr[nv] = (dr * 8 + (hl ^ (dr & 7))) * 8;
  }

  auto stage_kv = [&](int bb, int jn) {
#pragma unroll
    for (int i = 0; i < 2; i++) {
      int slot = i * 256 + tid;                       // 512 16B slots = 64x64 bf16
      int row = slot >> 3, c = (slot & 7) ^ (row & 7);
      __builtin_amdgcn_global_load_lds(AS1(Kg + ((size_t)jn * 64 + row) * 64 + c * 8),
                                       AS3(&Ksm[bb][0] + slot * 8), 16, 0, 0);
    }
#pragma unroll
    for (int i = 0; i < 2; i++) {
      int slot = i * 256 + tid;                       // 512 16B slots = 64x64 bf16
      int d = slot >> 3, c = (slot & 7) ^ (d & 7);
      __builtin_amdgcn_global_load_lds(AS1(Vtg + (size_t)d * 2048 + jn * 64 + c * 8),
                                       AS3(&Vsm[bb][0] + slot * 8), 16, 0, 0);
    }
  };

  f32x16 zc;
#pragma unroll
  for (int e = 0; e < 16; e++) zc[e] = 0.f;

  const int J = 2 * (qb + 1);              // 64-wide KV iters
  const int qrel = qb * 128 + w * 32;      // wave's first q row (global)
  const int qg = qrel + l31;               // this lane's q-row (softmax axis)

  bf16x8 aq[4];
#pragma unroll
  for (int kk = 0; kk < 4; kk++)
    aq[kk] = *(const bf16x8*)(Qg + (size_t)qg * 64 + kk * 16 + hl * 8);

  f32x16 Oacc[2];
#pragma unroll
  for (int e = 0; e < 16; e++) { Oacc[0][e] = 0.f; Oacc[1][e] = 0.f; }
  float Lpart = 0.f;

  int cur = 0;
  stage_kv(0, 0);

  for (int j = 0; j < J; j++) {
    asm volatile("s_waitcnt vmcnt(0)" ::: "memory");
    __syncthreads();
    if (j + 1 < J) stage_kv(cur ^ 1, j + 1);  // flies during compute

    const bf16_t* Kb = &Ksm[cur][0];
    const bf16_t* Vb = &Vsm[cur][0];
    const int k0 = j * 64;

    auto nt_body = [&](int nt, bool masked) {
      // S^T[k][q=l31] = sum_d K[k][d] * Q[q][d], k rows sigma-permuted.
      // Two independent 2-chains (sa: kk 0,2 / sb: kk 1,3) halve the dep latency.
      __builtin_amdgcn_s_setprio(1);
      bf16x8 a0 = *(const bf16x8*)(Kb + nt * 2048 + kadr[0]);
      bf16x8 a1 = *(const bf16x8*)(Kb + nt * 2048 + kadr[1]);
      f32x16 sa = __builtin_amdgcn_mfma_f32_32x32x16_bf16(a0, aq[0], zc, 0, 0, 0);
      f32x16 sb = __builtin_amdgcn_mfma_f32_32x32x16_bf16(a1, aq[1], zc, 0, 0, 0);
      bf16x8 a2 = *(const bf16x8*)(Kb + nt * 2048 + kadr[2]);
      bf16x8 a3 = *(const bf16x8*)(Kb + nt * 2048 + kadr[3]);
      sa = __builtin_amdgcn_mfma_f32_32x32x16_bf16(a2, aq[2], sa, 0, 0, 0);
      sb = __builtin_amdgcn_mfma_f32_32x32x16_bf16(a3, aq[3], sb, 0, 0, 0);
      __builtin_amdgcn_s_setprio(0);

      // lane's 16 values sit at k-offs hl*8 + (r&7) + 16*(r>>3)  (thanks to sigma)
      float p[16];
#pragma unroll
      for (int r = 0; r < 16; r++) {
        const int koff = hl * 8 + (r & 7) + 16 * (r >> 3);
        const float x = sa[r] + sb[r];
        p[r] = (masked && (koff > l31)) ? 0.f : __builtin_exp2f(x);
      }

      // L row-sum: in-register tree (partner half folded once at the end)
      {
        float a0s = p[0] + p[1], a1s = p[2] + p[3], a2s = p[4] + p[5], a3s = p[6] + p[7];
        float a4s = p[8] + p[9], a5s = p[10] + p[11], a6s = p[12] + p[13], a7s = p[14] + p[15];
        Lpart += ((a0s + a1s) + (a2s + a3s)) + ((a4s + a5s) + (a6s + a7s));
      }

      // P bf16 A-fragments, directly in-lane (no cross-lane ops)
      u32x4 w0, w1;
      w0[0] = pack_bf16x2(p[0], p[1]);   w0[1] = pack_bf16x2(p[2], p[3]);
      w0[2] = pack_bf16x2(p[4], p[5]);   w0[3] = pack_bf16x2(p[6], p[7]);
      w1[0] = pack_bf16x2(p[8], p[9]);   w1[1] = pack_bf16x2(p[10], p[11]);
      w1[2] = pack_bf16x2(p[12], p[13]); w1[3] = pack_bf16x2(p[14], p[15]);
      bf16x8 pa0 = __builtin_bit_cast(bf16x8, w0);  // k-offs nt*32 + 0..15
      bf16x8 pa1 = __builtin_bit_cast(bf16x8, w1);  // k-offs nt*32 + 16..31

      __builtin_amdgcn_s_setprio(1);
      // O += P @ V  (B-operand: n=l31=dv, k=hl*8+e along s)
#pragma unroll
      for (int nv = 0; nv < 2; nv++) {
        bf16x8 bv0 = *(const bf16x8*)(Vb + (vadr[nv] ^ ((nt * 4 + 0) * 8)));
        Oacc[nv] = __builtin_amdgcn_mfma_f32_32x32x16_bf16(pa0, bv0, Oacc[nv], 0, 0, 0);
        bf16x8 bv1 = *(const bf16x8*)(Vb + (vadr[nv] ^ ((nt * 4 + 2) * 8)));
        Oacc[nv] = __builtin_amdgcn_mfma_f32_32x32x16_bf16(pa1, bv1, Oacc[nv], 0, 0, 0);
      }
      __builtin_amdgcn_s_setprio(0);
    };

#pragma unroll
    for (int nt = 0; nt < 2; nt++) {
      const int kk0 = k0 + nt * 32;
      if (kk0 <= qrel) nt_body(nt, kk0 == qrel);  // kk0 > qrel: fully masked -> skip
    }
    cur ^= 1;
  }

  // epilogue: L for q=l31 lives per-lane; O rows are crow(r,hl) -> redistribute via
  // tiny wave-private LDS (broadcast reads are free)
  float Lf = Lpart + __shfl_xor(Lpart, 32, 64);
  if (hl == 0) Lsh[w * 32 + l31] = Lf;
  asm volatile("s_waitcnt lgkmcnt(0)" ::: "memory");  // same-wave ds_write -> ds_read
#pragma unroll
  for (int r = 0; r < 16; r++) {
    const int crow = (r & 3) + 8 * (r >> 2) + 4 * hl;
    const float rl = __builtin_amdgcn_rcpf(Lsh[w * 32 + crow]);
    const int qrow = qb * 128 + w * 32 + crow;
#pragma unroll
    for (int nv = 0; nv < 2; nv++)
      ctx[((size_t)b * 2048 + qrow) * 1024 + h * 64 + nv * 32 + l31] =
          (bf16_t)(Oacc[nv][r] * rl);
  }
}

// ---------------- out proj: out[8192,1024] = ctx @ Wout^T + b ----------------
// BK=64 + swizzled staging, same as gemm_qkv. XCD-band swizzle: m-tile 8a+b.
__global__ __launch_bounds__(256) void gemm_out_kernel(
    const bf16_t* __restrict__ A, const bf16_t* __restrict__ Bt,
    const float* __restrict__ bias, float* __restrict__ out) {
  __shared__ __align__(16) bf16_t As[128 * 64];
  __shared__ __align__(16) bf16_t Bs[128 * 64];
  const int tid = threadIdx.x;
  const int lane = tid & 63, wave = tid >> 6;
  const int quad = lane >> 4, l15 = lane & 15;
  const int wr = wave >> 1, wc = wave & 1;
  const int bid = blockIdx.x;
  const int mt_ = (bid & 7) * 8 + ((bid >> 3) & 7);  // m-tile 0..63
  const int nt_ = bid >> 6;                          // n-tile 0..7
  const int m0 = mt_ * 128, n0 = nt_ * 128;
  f32x4 acc[4][4];
  const f32x4 vzero = {0.f, 0.f, 0.f, 0.f};
#pragma unroll
  for (int i = 0; i < 4; i++)
#pragma unroll
    for (int j = 0; j < 4; j++) acc[i][j] = vzero;

  for (int kb = 0; kb < 1024; kb += 64) {
    __syncthreads();
#pragma unroll
    for (int i = 0; i < 4; i++) {
      int slot = i * 256 + tid;
      int row = slot >> 3, ch = slot & 7;
      int gch = ch ^ (row & 7);
      __builtin_amdgcn_global_load_lds(AS1(A + (size_t)(m0 + row) * 1024 + kb + gch * 8),
                                       AS3(As + slot * 8), 16, 0, 0);
    }
#pragma unroll
    for (int i = 0; i < 4; i++) {
      int slot = i * 256 + tid;
      int row = slot >> 3, ch = slot & 7;
      int gch = ch ^ (row & 7);
      __builtin_amdgcn_global_load_lds(AS1(Bt + (size_t)(n0 + row) * 1024 + kb + gch * 8),
                                       AS3(Bs + slot * 8), 16, 0, 0);
    }
    __builtin_amdgcn_s_waitcnt(0);
    __syncthreads();
#pragma unroll
    for (int ks = 0; ks < 2; ks++) {
      bf16x8 af[4], bfr[4];
#pragma unroll
      for (int t = 0; t < 4; t++) {
        int ra = wr * 64 + t * 16 + l15;
        af[t]  = *(const bf16x8*)(As + ra * 64 + ((ks * 4 + quad) ^ (ra & 7)) * 8);
        int rb = wc * 64 + t * 16 + l15;
        bfr[t] = *(const bf16x8*)(Bs + rb * 64 + ((ks * 4 + quad) ^ (rb & 7)) * 8);
      }
#pragma unroll
      for (int mt = 0; mt < 4; mt++)
#pragma unroll
        for (int nt = 0; nt < 4; nt++)
          acc[mt][nt] = __builtin_amdgcn_mfma_f32_16x16x32_bf16(af[mt], bfr[nt], acc[mt][nt], 0, 0, 0);
    }
  }
#pragma unroll
  for (int nt = 0; nt < 4; nt++) {
    int gn = n0 + wc * 64 + nt * 16 + l15;
    float bv = bias[gn];
#pragma unroll
    for (int mt = 0; mt < 4; mt++) {
#pragma unroll
      for (int r = 0; r < 4; r++) {
        int gm = m0 + wr * 64 + mt * 16 + quad * 4 + r;
        out[(size_t)gm * 1024 + gn] = acc[mt][nt][r] + bv;
      }
    }
  }
}

extern "C" void kernel_launch(void* const* d_in, const int* in_sizes, int n_in,
                              void* d_out, int out_size, void* d_ws, size_t ws_size,
                              hipStream_t stream) {
  (void)in_sizes; (void)n_in; (void)out_size; (void)ws_size;
  const float* X     = (const float*)d_in[0];  // [4,2048,1024]
  const float* W_qkv = (const float*)d_in[1];  // [1024,3072]
  const float* W_out = (const float*)d_in[2];  // [1024,1024]
  const float* b_out = (const float*)d_in[3];  // [1024]
  float* out = (float*)d_out;                  // [4,2048,1024] fp32

  char* ws = (char*)d_ws;
  bf16_t* Xb    = (bf16_t*)(ws);               // 16 MB
  bf16_t* Wqkvt = (bf16_t*)(ws + 16777216);    // 6 MB   [3072][1024]
  bf16_t* Woutt = (bf16_t*)(ws + 23068672);    // 2 MB   [1024][1024]
  bf16_t* Qb    = (bf16_t*)(ws + 25165824);    // 16 MB  [b,h,s,d]
  bf16_t* Kb    = (bf16_t*)(ws + 41943040);    // 16 MB  [b,h,s,d]
  bf16_t* Vt    = (bf16_t*)(ws + 58720256);    // 16 MB  [b,h,d,s] (written directly by GEMM)
  bf16_t* ctx   = (bf16_t*)(ws + 75497472);    // 16 MB  [b,s,1024]

  prep_kernel<<<12288, 256, 0, stream>>>(X, Xb, W_qkv, Wqkvt, W_out, Woutt);
  gemm_qkv_kernel<<<1536, 256, 0, stream>>>(Xb, Wqkvt, Qb, Kb, Vt);
  attn_kernel<<<dim3(1024), 256, 0, stream>>>(Qb, Kb, Vt, ctx);
  gemm_out_kernel<<<512, 256, 0, stream>>>(ctx, Woutt, b_out, out);
}